// Round 3
// baseline (256.293 us; speedup 1.0000x reference)
//
#include <hip/hip_runtime.h>

#define EPS_F 1e-5f

typedef float f32x4 __attribute__((ext_vector_type(4)));

// Output layout (floats):
//   [0, 2700)                : ref3d  (1,900,3)  = reference_points copy
//   [2700, 2700+5529600)     : sampled_feats (1,256,900,6,1,4)
//                              idx = 2700 + c*21600 + q*24 + n*4 + l
//   [5532300, 5537700)       : mask (1,1,900,6,1,1), idx = 5532300 + q*6 + n
//
// Grid: 5400 blocks = (q,n) pairs; 256 threads = channel c.
//   - 5400 blocks x 4 waves = 21600 waves -> load balance + TLP
//     (900-block variant regressed: 3.5 blocks/CU total, imbalance on tail)
//   - projection block-uniform -> scalar branches
//   - single l3-level cam_valid test (superset of all per-level ranges):
//     87.5% of blocks store zeros and exit with no per-level math
//   - valid blocks: branchless clamped gather, 16 independent loads in flight
//   - nontemporal store for the streamed (never re-read) output
__global__ __launch_bounds__(256) void fs_kernel(
    const float* __restrict__ f0, const float* __restrict__ f1,
    const float* __restrict__ f2, const float* __restrict__ f3,
    const float* __restrict__ ref_pts, const float* __restrict__ pc_range,
    const float* __restrict__ img_shape, const float* __restrict__ l2i,
    float* __restrict__ out)
{
    const int bid = blockIdx.x;
    const int n = bid % 6;          // camera
    const int q = bid / 6;          // query
    const int c = threadIdx.x;      // channel

    // ---- projection (uniform across block) ----
    const float X = ref_pts[q * 3 + 0] * (pc_range[3] - pc_range[0]) + pc_range[0];
    const float Y = ref_pts[q * 3 + 1] * (pc_range[4] - pc_range[1]) + pc_range[1];
    const float Z = ref_pts[q * 3 + 2] * (pc_range[5] - pc_range[2]) + pc_range[2];
    const float* M = l2i + n * 16;
    const float cx = M[0] * X + M[1] * Y + M[2]  * Z + M[3];
    const float cy = M[4] * X + M[5] * Y + M[6]  * Z + M[7];
    const float cz = M[8] * X + M[9] * Y + M[10] * Z + M[11];
    const float denom = fmaxf(cz, EPS_F);
    const float u = (cx / denom) / img_shape[1];   // x / 1600
    const float v = (cy / denom) / img_shape[0];   // y / 928
    const float xn = (u - 0.5f) * 2.0f;
    const float yn = (v - 0.5f) * 2.0f;

    // ---- mask output (one lane) ----
    if (threadIdx.x == 0) {
        const bool m = (cz > EPS_F) && (xn > -1.0f) && (xn < 1.0f)
                                    && (yn > -1.0f) && (yn < 1.0f);
        out[5532300 + q * 6 + n] = m ? 1.0f : 0.0f;
    }
    // ---- ref3d copy (3 lanes of the n==0 block for this q) ----
    if (n == 0 && threadIdx.x < 3) {
        out[q * 3 + threadIdx.x] = ref_pts[q * 3 + threadIdx.x];
    }

    float* const optr = out + 2700 + (size_t)c * 21600 + q * 24 + n * 4;

    // Camera-valid test at the WIDEST level (l=3: 15x25).
    // Any-corner-valid at level l <=> xn in [-1-1/W, 1+1/W), yn likewise;
    // the range grows as W,H shrink, so the l3 range contains l0..l2.
    // (verified correct against the harness in round 1)
    const float ix3  = ((xn + 1.0f) * 25.0f - 1.0f) * 0.5f;
    const float iy3  = ((yn + 1.0f) * 15.0f - 1.0f) * 0.5f;
    const float ix3f = floorf(ix3);
    const float iy3f = floorf(iy3);
    const bool cam_valid = (ix3f >= -1.0f) && (ix3f <= 24.0f)
                        && (iy3f >= -1.0f) && (iy3f <= 14.0f);

    f32x4 o = {0.0f, 0.0f, 0.0f, 0.0f};

    if (cam_valid) {                      // uniform branch
        const float* const feats[4] = {f0, f1, f2, f3};
        const int Hs[4] = {116, 58, 29, 15};
        const int Ws[4] = {200, 100, 50, 25};
        float accl[4];
        #pragma unroll
        for (int l = 0; l < 4; ++l) {
            const int W = Ws[l];
            const int H = Hs[l];
            const float ix = ((xn + 1.0f) * (float)W - 1.0f) * 0.5f;
            const float iy = ((yn + 1.0f) * (float)H - 1.0f) * 0.5f;
            const float ix0f = floorf(ix);
            const float iy0f = floorf(iy);
            const float wx1 = ix - ix0f, wx0 = 1.0f - wx1;
            const float wy1 = iy - iy0f, wy0 = 1.0f - wy1;
            const bool vx0 = (ix0f >= 0.0f)  && (ix0f <= (float)(W - 1));
            const bool vx1 = (ix0f >= -1.0f) && (ix0f <= (float)(W - 2));
            const bool vy0 = (iy0f >= 0.0f)  && (iy0f <= (float)(H - 1));
            const bool vy1 = (iy0f >= -1.0f) && (iy0f <= (float)(H - 2));

            // branchless: clamp indices, zero the weights of invalid corners
            const float w00 = (vy0 && vx0) ? wy0 * wx0 : 0.0f;
            const float w01 = (vy0 && vx1) ? wy0 * wx1 : 0.0f;
            const float w10 = (vy1 && vx0) ? wy1 * wx0 : 0.0f;
            const float w11 = (vy1 && vx1) ? wy1 * wx1 : 0.0f;

            const int x0 = (int)fminf(fmaxf(ix0f,        0.0f), (float)(W - 1));
            const int x1 = (int)fminf(fmaxf(ix0f + 1.0f, 0.0f), (float)(W - 1));
            const int y0 = (int)fminf(fmaxf(iy0f,        0.0f), (float)(H - 1));
            const int y1 = (int)fminf(fmaxf(iy0f + 1.0f, 0.0f), (float)(H - 1));

            const float* base = feats[l] + (size_t)(n * 256 + c) * (size_t)(H * W);
            const float* r0 = base + y0 * W;
            const float* r1 = base + y1 * W;
            // 4 independent loads; all 16 (4 levels) can be in flight at once
            const float v00 = r0[x0];
            const float v01 = r0[x1];
            const float v10 = r1[x0];
            const float v11 = r1[x1];
            accl[l] = w00 * v00 + w01 * v01 + w10 * v10 + w11 * v11;
        }
        o.x = accl[0]; o.y = accl[1]; o.z = accl[2]; o.w = accl[3];
    }

    // streamed output, never re-read: nontemporal store
    __builtin_nontemporal_store(o, (f32x4*)optr);
}

extern "C" void kernel_launch(void* const* d_in, const int* in_sizes, int n_in,
                              void* d_out, int out_size, void* d_ws, size_t ws_size,
                              hipStream_t stream) {
    const float* f0  = (const float*)d_in[0];  // (1,6,256,116,200)
    const float* f1  = (const float*)d_in[1];  // (1,6,256,58,100)
    const float* f2  = (const float*)d_in[2];  // (1,6,256,29,50)
    const float* f3  = (const float*)d_in[3];  // (1,6,256,15,25)
    const float* rp  = (const float*)d_in[4];  // (1,900,3)
    const float* pcr = (const float*)d_in[5];  // (6,)
    const float* ish = (const float*)d_in[6];  // (2,)
    const float* l2i = (const float*)d_in[7];  // (1,6,4,4)
    float* out = (float*)d_out;

    fs_kernel<<<5400, 256, 0, stream>>>(f0, f1, f2, f3, rp, pcr, ish, l2i, out);
}

// Round 4
// 235.809 us; speedup vs baseline: 1.0869x; 1.0869x over previous
//
#include <hip/hip_runtime.h>

#define EPS_F 1e-5f

// Output layout (floats):
//   [0, 2700)                : ref3d  (1,900,3)  = reference_points copy
//   [2700, 2700+5529600)     : sampled_feats (1,256,900,6,1,4)
//                              idx = 2700 + c*21600 + q*24 + n*4 + l
//   [5532300, 5537700)       : mask (1,1,900,6,1,1), idx = 5532300 + q*6 + n
//
// Grid: 5400 blocks = (q,n) pairs; 256 threads = channel c.
//   - 5400 blocks x 4 waves = 21600 waves -> load balance + TLP
//     (900-block variant regressed: 3.5 blocks/CU total, imbalance on tail)
//   - XCD swizzle: s = (bid%8)*675 + bid/8 (bijection, 5400=8*675) puts
//     consecutive (q,n) — which share output 64B lines — on the SAME XCD,
//     so partial lines combine in one L2 before eviction (per-XCD L2s are
//     not coherent; consecutive bids round-robin across XCDs).
//   - plain float4 store: nontemporal store regressed +20us (bypasses L2
//     write-combining -> partial-line HBM RMW). Do NOT use nt here.
//   - projection block-uniform -> scalar branches
//   - single l3-level cam_valid test (superset of all per-level ranges)
//   - valid blocks: branchless clamped gather, 16 independent loads in flight
__global__ __launch_bounds__(256) void fs_kernel(
    const float* __restrict__ f0, const float* __restrict__ f1,
    const float* __restrict__ f2, const float* __restrict__ f3,
    const float* __restrict__ ref_pts, const float* __restrict__ pc_range,
    const float* __restrict__ img_shape, const float* __restrict__ l2i,
    float* __restrict__ out)
{
    const int bid = blockIdx.x;
    // XCD-aware swizzle: all 675 s-consecutive blocks of one XCD share
    // output lines only among themselves.
    const int s = (bid & 7) * 675 + (bid >> 3);
    const int n = s % 6;            // camera
    const int q = s / 6;            // query
    const int c = threadIdx.x;      // channel

    // ---- projection (uniform across block) ----
    const float X = ref_pts[q * 3 + 0] * (pc_range[3] - pc_range[0]) + pc_range[0];
    const float Y = ref_pts[q * 3 + 1] * (pc_range[4] - pc_range[1]) + pc_range[1];
    const float Z = ref_pts[q * 3 + 2] * (pc_range[5] - pc_range[2]) + pc_range[2];
    const float* M = l2i + n * 16;
    const float cx = M[0] * X + M[1] * Y + M[2]  * Z + M[3];
    const float cy = M[4] * X + M[5] * Y + M[6]  * Z + M[7];
    const float cz = M[8] * X + M[9] * Y + M[10] * Z + M[11];
    const float denom = fmaxf(cz, EPS_F);
    const float u = (cx / denom) / img_shape[1];   // x / 1600
    const float v = (cy / denom) / img_shape[0];   // y / 928
    const float xn = (u - 0.5f) * 2.0f;
    const float yn = (v - 0.5f) * 2.0f;

    // ---- mask output (one lane) ----
    if (threadIdx.x == 0) {
        const bool m = (cz > EPS_F) && (xn > -1.0f) && (xn < 1.0f)
                                    && (yn > -1.0f) && (yn < 1.0f);
        out[5532300 + q * 6 + n] = m ? 1.0f : 0.0f;
    }
    // ---- ref3d copy (3 lanes of the n==0 block for this q) ----
    if (n == 0 && threadIdx.x < 3) {
        out[q * 3 + threadIdx.x] = ref_pts[q * 3 + threadIdx.x];
    }

    float* const optr = out + 2700 + (size_t)c * 21600 + q * 24 + n * 4;

    // Camera-valid test at the WIDEST level (l=3: 15x25).
    // Any-corner-valid at level l <=> xn in (-1-1/W, 1+1/W), yn likewise;
    // the range grows as W,H shrink, so the l3 range contains l0..l2.
    // (verified correct against the harness in rounds 1 and 3)
    const float ix3  = ((xn + 1.0f) * 25.0f - 1.0f) * 0.5f;
    const float iy3  = ((yn + 1.0f) * 15.0f - 1.0f) * 0.5f;
    const float ix3f = floorf(ix3);
    const float iy3f = floorf(iy3);
    const bool cam_valid = (ix3f >= -1.0f) && (ix3f <= 24.0f)
                        && (iy3f >= -1.0f) && (iy3f <= 14.0f);

    float4 o;
    o.x = 0.0f; o.y = 0.0f; o.z = 0.0f; o.w = 0.0f;

    if (cam_valid) {                      // uniform branch
        const float* const feats[4] = {f0, f1, f2, f3};
        const int Hs[4] = {116, 58, 29, 15};
        const int Ws[4] = {200, 100, 50, 25};
        float accl[4];
        #pragma unroll
        for (int l = 0; l < 4; ++l) {
            const int W = Ws[l];
            const int H = Hs[l];
            const float ix = ((xn + 1.0f) * (float)W - 1.0f) * 0.5f;
            const float iy = ((yn + 1.0f) * (float)H - 1.0f) * 0.5f;
            const float ix0f = floorf(ix);
            const float iy0f = floorf(iy);
            const float wx1 = ix - ix0f, wx0 = 1.0f - wx1;
            const float wy1 = iy - iy0f, wy0 = 1.0f - wy1;
            const bool vx0 = (ix0f >= 0.0f)  && (ix0f <= (float)(W - 1));
            const bool vx1 = (ix0f >= -1.0f) && (ix0f <= (float)(W - 2));
            const bool vy0 = (iy0f >= 0.0f)  && (iy0f <= (float)(H - 1));
            const bool vy1 = (iy0f >= -1.0f) && (iy0f <= (float)(H - 2));

            // branchless: clamp indices, zero the weights of invalid corners
            const float w00 = (vy0 && vx0) ? wy0 * wx0 : 0.0f;
            const float w01 = (vy0 && vx1) ? wy0 * wx1 : 0.0f;
            const float w10 = (vy1 && vx0) ? wy1 * wx0 : 0.0f;
            const float w11 = (vy1 && vx1) ? wy1 * wx1 : 0.0f;

            const int x0 = (int)fminf(fmaxf(ix0f,        0.0f), (float)(W - 1));
            const int x1 = (int)fminf(fmaxf(ix0f + 1.0f, 0.0f), (float)(W - 1));
            const int y0 = (int)fminf(fmaxf(iy0f,        0.0f), (float)(H - 1));
            const int y1 = (int)fminf(fmaxf(iy0f + 1.0f, 0.0f), (float)(H - 1));

            const float* base = feats[l] + (size_t)(n * 256 + c) * (size_t)(H * W);
            const float* r0 = base + y0 * W;
            const float* r1 = base + y1 * W;
            // 4 independent loads; all 16 (4 levels) can be in flight at once
            const float v00 = r0[x0];
            const float v01 = r0[x1];
            const float v10 = r1[x0];
            const float v11 = r1[x1];
            accl[l] = w00 * v00 + w01 * v01 + w10 * v10 + w11 * v11;
        }
        o.x = accl[0]; o.y = accl[1]; o.z = accl[2]; o.w = accl[3];
    }

    *(float4*)optr = o;
}

extern "C" void kernel_launch(void* const* d_in, const int* in_sizes, int n_in,
                              void* d_out, int out_size, void* d_ws, size_t ws_size,
                              hipStream_t stream) {
    const float* f0  = (const float*)d_in[0];  // (1,6,256,116,200)
    const float* f1  = (const float*)d_in[1];  // (1,6,256,58,100)
    const float* f2  = (const float*)d_in[2];  // (1,6,256,29,50)
    const float* f3  = (const float*)d_in[3];  // (1,6,256,15,25)
    const float* rp  = (const float*)d_in[4];  // (1,900,3)
    const float* pcr = (const float*)d_in[5];  // (6,)
    const float* ish = (const float*)d_in[6];  // (2,)
    const float* l2i = (const float*)d_in[7];  // (1,6,4,4)
    float* out = (float*)d_out;

    fs_kernel<<<5400, 256, 0, stream>>>(f0, f1, f2, f3, rp, pcr, ish, l2i, out);
}